// Round 2
// baseline (99.325 us; speedup 1.0000x reference)
//
#include <hip/hip_runtime.h>
#include <cstdint>

// Problem constants (from reference file)
constexpr int Bb = 8;     // batch
constexpr int Cc = 256;   // channels
constexpr int Tt = 1024;  // time
constexpr int Mm = 512;   // num_masked
constexpr int Kk = 100;   // negatives per position
#define EPSF 1e-8f
#define INV_TEMP 10.0f

// ---------------------------------------------------------------------------
// Kernel A: extract masked indices per batch row, ascending t order.
// (unchanged from R1 — verified absmax 0.0)
// ---------------------------------------------------------------------------
__global__ __launch_bounds__(1024)
void cl_mask_extract(const void* __restrict__ mask, int* __restrict__ idx) {
    const int b    = blockIdx.x;
    const int tid  = threadIdx.x;          // 0..1023
    const int lane = tid & 63;
    const int wave = tid >> 6;             // 0..15

    __shared__ int wcnt8[16];
    __shared__ int wcnt32[16];
    __shared__ int wcntp[16];
    __shared__ int layout_s;

    const uint8_t* p8  = (const uint8_t*)mask;
    const int32_t* p32 = (const int32_t*)mask;
    unsigned long long bal8  = __ballot(p8[tid]  != 0);
    unsigned long long bal32 = __ballot(p32[tid] != 0);
    if (lane == 0) { wcnt8[wave] = __popcll(bal8); wcnt32[wave] = __popcll(bal32); }
    __syncthreads();
    if (tid == 0) {
        int c8 = 0, c32 = 0;
        for (int w = 0; w < 16; ++w) { c8 += wcnt8[w]; c32 += wcnt32[w]; }
        layout_s = (c8 == Mm) ? 1 : ((c32 == Mm) ? 4 : 8);
    }
    __syncthreads();
    const int esz = layout_s;

    const long long off = (long long)b * Tt + tid;
    int bit;
    if (esz == 1)      bit = (p8[off]  != 0);
    else if (esz == 4) bit = (p32[off] != 0);
    else               bit = (((const int64_t*)mask)[off] != 0);

    unsigned long long bp = __ballot(bit);
    if (lane == 0) wcntp[wave] = __popcll(bp);
    __syncthreads();
    int base = 0;
    for (int w = 0; w < wave; ++w) base += wcntp[w];
    const int rank = base + __popcll(bp & ((1ull << lane) - 1ull));
    if (bit && rank < Mm) idx[b * Mm + rank] = tid;
}

// ---------------------------------------------------------------------------
// Kernel P: tiled transpose [b][c][t] -> [b][t][c] for context and positive.
// grid = (Bb*32, 2): blockIdx.x = b*32 + tt (32-t tile), blockIdx.y = src sel.
// 256 threads. Read: 128B-contiguous segments per 8-lane group (coalesced).
// Write: 1KB-contiguous per wave (coalesced). LDS pad=4 keeps float4 reads
// 16B-aligned; scalar write conflicts are 4-way max (negligible vs HBM).
// ---------------------------------------------------------------------------
__global__ __launch_bounds__(256)
void cl_transpose(const float* __restrict__ ctx, const float* __restrict__ pos,
                  float* __restrict__ ctxT, float* __restrict__ posT) {
    const int bx = blockIdx.x;             // 0..255
    const int b  = bx >> 5;
    const int tt = bx & 31;
    const float* __restrict__ src = blockIdx.y ? pos : ctx;
    float*       __restrict__ dst = blockIdx.y ? posT : ctxT;
    const int tid   = threadIdx.x;
    const int t4    = tid & 7;             // float4-chunk over t
    const int c_off = tid >> 3;            // 0..31

    __shared__ __align__(16) float lds[32][260];

    const int tbase = tt * 32;
    #pragma unroll
    for (int p = 0; p < 8; ++p) {
        const int c = p * 32 + c_off;
        const float4 v = *(const float4*)(src + ((long long)(b * Cc + c) * Tt + tbase + t4 * 4));
        lds[t4 * 4 + 0][c] = v.x;
        lds[t4 * 4 + 1][c] = v.y;
        lds[t4 * 4 + 2][c] = v.z;
        lds[t4 * 4 + 3][c] = v.w;
    }
    __syncthreads();

    const int lane = tid & 63;
    const int wave = tid >> 6;
    #pragma unroll
    for (int p = 0; p < 8; ++p) {
        const int t_l = p * 4 + wave;
        const float4 v = *(const float4*)(&lds[t_l][lane * 4]);
        *(float4*)(dst + ((long long)(b * Tt + tbase + t_l) * Cc + lane * 4)) = v;
    }
}

// ---------------------------------------------------------------------------
// Kernel B: per-(b,m) cosine logits + logsumexp.
// grid = Bb*Mm (=4096) blocks, 256 threads (4 waves).
// Gather is now two contiguous 1KB row reads from the transposed buffers.
// Normalization by 1/||ctx|| deferred to the LSE phase (shared by all 101
// logits) -> k-loop has no dependency on the block-wide norm reduce.
// ---------------------------------------------------------------------------
__global__ __launch_bounds__(256)
void cl_main(const float* __restrict__ ctxT,
             const float* __restrict__ posT,
             const float* __restrict__ negatives,
             const int*   __restrict__ idx,
             float*       __restrict__ lossbuf) {
    const int bm   = blockIdx.x;           // 0..4095
    const int b    = bm >> 9;              // /512
    const int tid  = threadIdx.x;          // 0..255
    const int lane = tid & 63;
    const int wave = tid >> 6;             // 0..3
    const int q    = lane & 15;
    const int ks   = lane >> 4;            // 0..3

    __shared__ __align__(16) float ctx_s[Cc];
    __shared__ float red[4][3];
    __shared__ float logits[Kk + 1];

    const int t = idx[bm];
    const long long row = ((long long)b * Tt + t) * Cc;

    // coalesced gather of ctx/pos rows
    const float cv = ctxT[row + tid];
    const float pv = posT[row + tid];
    ctx_s[tid] = cv;

    // block reduce: ||ctx||^2, ||pos||^2, dot(ctx,pos) -> red[][]
    float s0 = cv * cv, s1 = pv * pv, s2 = cv * pv;
    #pragma unroll
    for (int d = 32; d >= 1; d >>= 1) {
        s0 += __shfl_xor(s0, d);
        s1 += __shfl_xor(s1, d);
        s2 += __shfl_xor(s2, d);
    }
    if (lane == 0) { red[wave][0] = s0; red[wave][1] = s1; red[wave][2] = s2; }
    __syncthreads();

    // each lane's 16 ctx values (raw, unnormalized) -> registers
    const float4* c4 = (const float4*)ctx_s;
    float4 cr[4];
    #pragma unroll
    for (int j = 0; j < 4; ++j) cr[j] = c4[j * 16 + q];

    // negatives stream: 16 k per iteration (4 waves x 4 sub-k)
    const long long nbase = (long long)bm * Kk * Cc;
    #pragma unroll 2
    for (int it = 0; it < 7; ++it) {
        const int k = it * 16 + wave * 4 + ks;
        float dotp = 0.f, sq = 0.f;
        if (k < Kk) {
            const float4* np4 = (const float4*)(negatives + nbase + (long long)k * Cc);
            #pragma unroll
            for (int j = 0; j < 4; ++j) {
                const float4 nv = np4[j * 16 + q];
                dotp += cr[j].x * nv.x + cr[j].y * nv.y + cr[j].z * nv.z + cr[j].w * nv.w;
                sq   += nv.x * nv.x + nv.y * nv.y + nv.z * nv.z + nv.w * nv.w;
            }
        }
        #pragma unroll
        for (int d = 1; d <= 8; d <<= 1) {
            dotp += __shfl_xor(dotp, d);
            sq   += __shfl_xor(sq, d);
        }
        if (k < Kk && q == 0) {
            const float nb = fmaxf(sqrtf(sq), EPSF);
            logits[1 + k] = dotp / nb;   // raw: missing 1/||ctx|| and 1/TEMP
        }
    }
    __syncthreads();

    // logsumexp over 101 logits (wave 0); apply shared scale 10/||ctx|| here
    if (wave == 0) {
        const float na2 = red[0][0] + red[1][0] + red[2][0] + red[3][0];
        const float np2 = red[0][1] + red[1][1] + red[2][1] + red[3][1];
        const float dcp = red[0][2] + red[1][2] + red[2][2] + red[3][2];
        const float na = fmaxf(sqrtf(na2), EPSF);
        const float np = fmaxf(sqrtf(np2), EPSF);
        const float scale = INV_TEMP / na;

        const float a_raw = (lane == 0) ? (dcp / np) : logits[lane];
        const float b_raw = (lane + 64 <= Kk) ? logits[lane + 64] : -3e28f;
        const float a  = a_raw * scale;
        const float bb = b_raw * scale;

        float mx = fmaxf(a, bb);
        #pragma unroll
        for (int d = 32; d >= 1; d >>= 1) mx = fmaxf(mx, __shfl_xor(mx, d));
        float e = expf(a - mx) + expf(bb - mx);
        #pragma unroll
        for (int d = 32; d >= 1; d >>= 1) e += __shfl_xor(e, d);
        const float logit0 = __shfl(a, 0);
        if (lane == 0) lossbuf[bm] = mx + logf(e) - logit0;
    }
}

// ---------------------------------------------------------------------------
// Kernel C: deterministic mean over 4096 per-(b,m) losses.
// ---------------------------------------------------------------------------
__global__ __launch_bounds__(256)
void cl_reduce(const float* __restrict__ lossbuf, float* __restrict__ out) {
    const int tid = threadIdx.x;   // 0..255
    float s = 0.f;
    #pragma unroll
    for (int i = 0; i < 16; ++i) s += lossbuf[tid * 16 + i];
    #pragma unroll
    for (int d = 32; d >= 1; d >>= 1) s += __shfl_xor(s, d);
    __shared__ float ws[4];
    if ((tid & 63) == 0) ws[tid >> 6] = s;
    __syncthreads();
    if (tid == 0) out[0] = (ws[0] + ws[1] + ws[2] + ws[3]) * (1.0f / (Bb * Mm));
}

extern "C" void kernel_launch(void* const* d_in, const int* in_sizes, int n_in,
                              void* d_out, int out_size, void* d_ws, size_t ws_size,
                              hipStream_t stream) {
    const float* context   = (const float*)d_in[0];
    const float* positive  = (const float*)d_in[1];
    const float* negatives = (const float*)d_in[2];
    const void*  mask      = d_in[3];
    // d_in[4] = num_masked (512) — hardcoded as Mm.

    // workspace layout (needs ~16.05 MB; harness poison-fills show ws >> this)
    float* ctxT    = (float*)d_ws;                                  // 8 MB
    float* posT    = ctxT + (size_t)Bb * Tt * Cc;                   // 8 MB
    int*   idx     = (int*)(posT + (size_t)Bb * Tt * Cc);           // 16 KB
    float* lossbuf = (float*)(idx + Bb * Mm);                       // 16 KB

    cl_mask_extract<<<Bb, 1024, 0, stream>>>(mask, idx);
    cl_transpose<<<dim3(Bb * 32, 2), 256, 0, stream>>>(context, positive, ctxT, posT);
    cl_main<<<Bb * Mm, 256, 0, stream>>>(ctxT, posT, negatives, idx, lossbuf);
    cl_reduce<<<1, 256, 0, stream>>>(lossbuf, (float*)d_out);
}